// Round 11
// baseline (142.342 us; speedup 1.0000x reference)
//
#include <hip/hip_runtime.h>
#include <hip/hip_bf16.h>

using bf16x8 = __attribute__((ext_vector_type(8))) __bf16;
using f32x4  = __attribute__((ext_vector_type(4))) float;

#define MTOT   16384
#define DMODEL 1024
#define DSTATE 64
#define KBIG   1088

__device__ __forceinline__ ushort f2b(float f) {
  __hip_bfloat16 h = __float2bfloat16(f);
  return *reinterpret_cast<ushort*>(&h);
}

// async global->LDS, 16 bytes per lane. LDS dest = wave-uniform base + lane*16.
__device__ __forceinline__ void gld_lds16(const ushort* g, const char* l) {
  using gptr_t = const __attribute__((address_space(1))) uint32_t*;
  using lptr_t = __attribute__((address_space(3))) uint32_t*;
  __builtin_amdgcn_global_load_lds(
      reinterpret_cast<gptr_t>(reinterpret_cast<uintptr_t>(g)),
      reinterpret_cast<lptr_t>(static_cast<uint32_t>(reinterpret_cast<uintptr_t>(l))),
      16, 0, 0);
}

#define BARRIER() do { asm volatile("" ::: "memory"); __builtin_amdgcn_s_barrier(); asm volatile("" ::: "memory"); } while (0)
#define VMCNT0() asm volatile("s_waitcnt vmcnt(0)" ::: "memory")

// ---------------- prep params ----------------
__global__ void prep_params(const float* __restrict__ A_diag, const float* __restrict__ B,
                            const float* __restrict__ C, const float* __restrict__ D,
                            ushort* __restrict__ Wt, ushort* __restrict__ Btu,
                            float* __restrict__ aSig) {
  int i = blockIdx.x * blockDim.x + threadIdx.x;
  int stride = gridDim.x * blockDim.x;
  for (int idx = i; idx < DMODEL * KBIG; idx += stride) {
    int n = idx / KBIG, k = idx % KBIG;
    float v = (k < DSTATE) ? C[k * DMODEL + n] : D[(size_t)(k - DSTATE) * DMODEL + n];
    Wt[idx] = f2b(v);
  }
  for (int idx = i; idx < DSTATE * DMODEL; idx += stride) {
    int s = idx >> 10, k = idx & 1023;
    Btu[idx] = f2b(B[k * DSTATE + s]);
  }
  if (i < DSTATE) aSig[i] = 1.0f / (1.0f + expf(-A_diag[i]));
}

// ---------------- fused: x -> Z(bf16), u = x@B -> chunk-local scan -> Uloc, carry ---------
__global__ __launch_bounds__(256) void fused_xu(const float* __restrict__ x,
    const ushort* __restrict__ Btu, const float* __restrict__ aSig,
    ushort* __restrict__ Z, float* __restrict__ Uloc, float* __restrict__ carry) {
  __shared__ ushort As[64][136];
  __shared__ float  Ul[64][68];
  int tid = threadIdx.x;
  int w = tid >> 6, lane = tid & 63;
  int l16 = lane & 15, lh = lane >> 4;
  int row0 = blockIdx.x * 64;

  f32x4 acc[4] = {};
  float4 xv[4][2];
#pragma unroll
  for (int p = 0; p < 4; ++p) {
    int fi = p * 256 + tid;
    int r = fi >> 4, kq = fi & 15;
    const float* src = x + (size_t)(row0 + r) * 1024 + kq * 8;
    xv[p][0] = *reinterpret_cast<const float4*>(src);
    xv[p][1] = *reinterpret_cast<const float4*>(src + 4);
  }
  for (int c = 0; c < 8; ++c) {
    int k0 = c * 128;
#pragma unroll
    for (int p = 0; p < 4; ++p) {
      int fi = p * 256 + tid;
      int r = fi >> 4, kq = fi & 15;
      ushort o[8] = {f2b(xv[p][0].x), f2b(xv[p][0].y), f2b(xv[p][0].z), f2b(xv[p][0].w),
                     f2b(xv[p][1].x), f2b(xv[p][1].y), f2b(xv[p][1].z), f2b(xv[p][1].w)};
      uint4 pk = *reinterpret_cast<uint4*>(o);
      *reinterpret_cast<uint4*>(&Z[(size_t)(row0 + r) * KBIG + DSTATE + k0 + kq * 8]) = pk;
      *reinterpret_cast<uint4*>(&As[r][kq * 8]) = pk;
    }
    __syncthreads();
    if (c < 7) {
      int k1 = k0 + 128;
#pragma unroll
      for (int p = 0; p < 4; ++p) {
        int fi = p * 256 + tid;
        int r = fi >> 4, kq = fi & 15;
        const float* src = x + (size_t)(row0 + r) * 1024 + k1 + kq * 8;
        xv[p][0] = *reinterpret_cast<const float4*>(src);
        xv[p][1] = *reinterpret_cast<const float4*>(src + 4);
      }
    }
#pragma unroll
    for (int ks = 0; ks < 4; ++ks) {
      bf16x8 af = *reinterpret_cast<const bf16x8*>(&As[w * 16 + l16][ks * 32 + lh * 8]);
#pragma unroll
      for (int n = 0; n < 4; ++n) {
        bf16x8 bf = *reinterpret_cast<const bf16x8*>(
            &Btu[(size_t)(n * 16 + l16) * 1024 + k0 + ks * 32 + lh * 8]);
        acc[n] = __builtin_amdgcn_mfma_f32_16x16x32_bf16(af, bf, acc[n], 0, 0, 0);
      }
    }
    __syncthreads();
  }
#pragma unroll
  for (int n = 0; n < 4; ++n)
#pragma unroll
    for (int j = 0; j < 4; ++j)
      Ul[w * 16 + lh * 4 + j][n * 16 + l16] = acc[n][j];
  __syncthreads();
  int s = lane;
  float as = aSig[s];
  float h = 0.0f;
  int g = blockIdx.x * 4 + w;
#pragma unroll
  for (int i = 0; i < 16; ++i) {
    h = fmaf(as, h, Ul[w * 16 + i][s]);
    Uloc[(size_t)(g * 16 + i) * 64 + s] = h;
  }
  carry[(size_t)g * 64 + s] = h;
}

// ---------------- scan fix (merged): redundant batched prefix + apply + write Z ------
__global__ __launch_bounds__(256) void scan_fix2(const float* __restrict__ aSig,
    const float* __restrict__ Uloc, const float* __restrict__ carry,
    ushort* __restrict__ Z) {
  int w = threadIdx.x >> 6, s = threadIdx.x & 63;
  int g = blockIdx.x * 4 + w;          // 0..1023
  int b = g >> 8, c = g & 255;
  float as = aSig[s];
  float aL = as;
#pragma unroll
  for (int q = 0; q < 4; ++q) aL *= aL;  // as^16
  const float* cb = carry + ((size_t)b << 8) * 64 + s;
  float H = 0.0f;
  for (int c0 = 0; c0 < 256; c0 += 16) {
    if (c0 >= c) break;                  // wave-uniform
    float v[16];
#pragma unroll
    for (int i = 0; i < 16; ++i) v[i] = cb[(size_t)(c0 + i) * 64];
#pragma unroll
    for (int i = 0; i < 16; ++i)
      if (c0 + i < c) H = fmaf(aL, H, v[i]);   // wave-uniform predicate
  }
  float p = as;
  size_t ubase = (size_t)g * 16 * 64 + s;
  size_t zbase = (size_t)(g * 16) * KBIG + s;
#pragma unroll
  for (int i = 0; i < 16; ++i) {
    float h = fmaf(p, H, Uloc[ubase + (size_t)i * 64]);
    p *= as;
    Z[zbase + (size_t)i * KBIG] = f2b(h);
  }
}

// ---------------- 128x256 GEMM, B-from-global, 2 blocks/CU: y = Z @ Wt^T ----------------
// 512 blocks (2/CU -> cross-block pipe overlap), 8 waves (2x4), wave tile 64x64.
// A: LDS dbuf 2x16KB (R5-proven swizzle/stage, conflict-free reads).
// B: fragments loaded DIRECTLY from global (Wt 2.2MB, L2-resident/XCD) — no LDS.
// One barrier/tile. In-order vmcnt retire: compiler's B-frag waits transitively
// drain the earlier-issued A stages; VMCNT0 before barrier is then ~free.
// Re-stage hazard (iter t+1 overwrites buf read at iter t): reads issued pre-barrier,
// gld_lds of next iter lands >=200cy post-barrier (R5-validated ordering).
__global__ __launch_bounds__(512) void gemm256(const ushort* __restrict__ A, int lda,
                                               const ushort* __restrict__ Bt, int ldb,
                                               float* __restrict__ Cc, int ldc, int K) {
  extern __shared__ __align__(128) char smem[];   // 2 x 16 KB A bufs
  const int tid = threadIdx.x;
  const int wid = tid >> 6, lane = tid & 63;
  const int wm = wid >> 2, wn = wid & 3;          // 2 x 4 wave grid
  const int l16 = lane & 15, lh = lane >> 4;

  int bid = blockIdx.x;
  int swz = (bid & 7) * ((int)gridDim.x >> 3) + (bid >> 3);  // 512 % 8 == 0
  const int bmRow = (swz >> 2) * 128;   // 128 row-tiles
  const int bnCol = (swz & 3) * 256;    // 4 col-tiles
  const int NT = K / 64;                // 17

  const int cswz = ((lh ^ (l16 & 7)) << 4);
  const int sRow = lane >> 3;
  const int sCol = (((lane & 7) ^ (lane >> 3)) << 3);

  // wave wid stages rows wid*16 .. wid*16+15 (two 8-row 1KB calls)
  const ushort* aBase = A + (size_t)(bmRow + wid * 16 + sRow) * lda + sCol;
  char* aDst = smem + (wid * 16) * 128;

  f32x4 acc[4][4] = {};
  bf16x8 aC[4], aN[4], bC[4], bN[4];

  auto stageA = [&](int buf, int t) {
    const ushort* g = aBase + (size_t)t * 64;
    char* d = aDst + buf;
    gld_lds16(g, d);
    gld_lds16(g + (size_t)8 * lda, d + 8 * 128);
  };
  auto readA = [&](bf16x8 (&dst)[4], int buf, int ks) {
#pragma unroll
    for (int m = 0; m < 4; ++m)
      dst[m] = *reinterpret_cast<const bf16x8*>(
          smem + buf + (wm * 64 + m * 16 + l16) * 128 + (cswz ^ (ks << 6)));
  };
  auto loadB = [&](bf16x8 (&dst)[4], int t, int ks) {
#pragma unroll
    for (int n = 0; n < 4; ++n)
      dst[n] = *reinterpret_cast<const bf16x8*>(
          Bt + (size_t)(bnCol + wn * 64 + n * 16 + l16) * ldb + t * 64 + ks * 32 + lh * 8);
  };
  auto mfmaK = [&](bf16x8 (&a4)[4], bf16x8 (&b4)[4]) {
    __builtin_amdgcn_s_setprio(1);
#pragma unroll
    for (int m = 0; m < 4; ++m)
#pragma unroll
      for (int n = 0; n < 4; ++n)
        acc[m][n] = __builtin_amdgcn_mfma_f32_16x16x32_bf16(a4[m], b4[n], acc[m][n], 0, 0, 0);
    __builtin_amdgcn_s_setprio(0);
  };

  // prologue: stage tile 0 into buf 0
  stageA(0, 0);
  VMCNT0();
  BARRIER();

  for (int t = 0; t < NT; ++t) {
    const int buf = (t & 1) << 14;           // 0 / 16384
    if (t + 1 < NT) stageA(buf ^ 16384, t + 1);
    loadB(bC, t, 0); loadB(bN, t, 1);        // global (L2); issued after stages
    readA(aC, buf, 0); readA(aN, buf, 1);    // LDS, conflict-free pattern
    mfmaK(aC, bC);                           // ks0
    mfmaK(aN, bN);                           // ks1 (B-wait drains stages in-order)
    VMCNT0();                                // ~free: stages already retired
    BARRIER();                               // publish buf^1; guard next re-stage
  }

  // epilogue: C/D 16x16 layout: col = l16, row = lh*4 + j
#pragma unroll
  for (int m = 0; m < 4; ++m)
#pragma unroll
    for (int n = 0; n < 4; ++n)
#pragma unroll
      for (int j = 0; j < 4; ++j) {
        int r = bmRow + wm * 64 + m * 16 + lh * 4 + j;
        int c = bnCol + wn * 64 + n * 16 + l16;
        Cc[(size_t)r * ldc + c] = acc[m][n][j];
      }
}

extern "C" void kernel_launch(void* const* d_in, const int* in_sizes, int n_in,
                              void* d_out, int out_size, void* d_ws, size_t ws_size,
                              hipStream_t stream) {
  const float* x      = (const float*)d_in[0];
  const float* A_diag = (const float*)d_in[1];
  const float* B      = (const float*)d_in[2];
  const float* C      = (const float*)d_in[3];
  const float* D      = (const float*)d_in[4];
  float* y = (float*)d_out;

  char* w = (char*)d_ws;
  ushort* Z     = (ushort*)(w);                 // [16384][1088] bf16  35,651,584
  ushort* Wt    = (ushort*)(w + 35651584);      // [1024][1088] bf16    2,228,224
  ushort* Btu   = (ushort*)(w + 37879808);      // [64][1024] bf16        131,072
  float*  Uloc  = (float*) (w + 38010880);      // [16384][64] f32      4,194,304
  float*  carry = (float*) (w + 42205184);      // [1024][64] f32         262,144
  float*  aSig  = (float*) (w + 42467328);      // [64] f32

  (void)hipFuncSetAttribute(reinterpret_cast<const void*>(&gemm256),
                            hipFuncAttributeMaxDynamicSharedMemorySize, 65536);

  prep_params<<<dim3(1024), dim3(256), 0, stream>>>(A_diag, B, C, D, Wt, Btu, aSig);
  fused_xu<<<dim3(256), dim3(256), 0, stream>>>(x, Btu, aSig, Z, Uloc, carry);
  scan_fix2<<<dim3(256), dim3(256), 0, stream>>>(aSig, Uloc, carry, Z);
  // y = [h|x] @ [C;D] : M=16384, N=1024, K=1088  (128x256 tiles -> 512 blocks, 2/CU)
  gemm256<<<dim3(128 * 4), dim3(512), 32768, stream>>>(Z, KBIG, Wt, KBIG, y, DMODEL, KBIG);
}

// Round 12
// 96.300 us; speedup vs baseline: 1.4781x; 1.4781x over previous
//
#include <hip/hip_runtime.h>
#include <hip/hip_bf16.h>

using bf16x8 = __attribute__((ext_vector_type(8))) __bf16;
using f32x4  = __attribute__((ext_vector_type(4))) float;

#define MTOT   16384
#define DMODEL 1024
#define DSTATE 64
#define KBIG   1088

__device__ __forceinline__ ushort f2b(float f) {
  __hip_bfloat16 h = __float2bfloat16(f);
  return *reinterpret_cast<ushort*>(&h);
}

// async global->LDS, 16 bytes per lane. LDS dest = wave-uniform base + lane*16.
__device__ __forceinline__ void gld_lds16(const ushort* g, const char* l) {
  using gptr_t = const __attribute__((address_space(1))) uint32_t*;
  using lptr_t = __attribute__((address_space(3))) uint32_t*;
  __builtin_amdgcn_global_load_lds(
      reinterpret_cast<gptr_t>(reinterpret_cast<uintptr_t>(g)),
      reinterpret_cast<lptr_t>(static_cast<uint32_t>(reinterpret_cast<uintptr_t>(l))),
      16, 0, 0);
}

#define BARRIER() do { asm volatile("" ::: "memory"); __builtin_amdgcn_s_barrier(); asm volatile("" ::: "memory"); } while (0)
#define VMCNT4() asm volatile("s_waitcnt vmcnt(4)" ::: "memory")
#define VMCNT0() asm volatile("s_waitcnt vmcnt(0)" ::: "memory")

// ---------------- prep: coalesced tile-transpose for Wt, Btu; aSig ----------------
// Virtual S[1088][1024]: rows 0-63 = C, 64-1087 = D. Wt[n][k] = bf16(S[k][n]).
// Blocks 0..271: 64x64 tiles of Wt (17 k-tiles x 16 n-tiles).
// Blocks 272..287: B [1024][64] -> Btu [64][1024] (16 k-tiles).
__global__ __launch_bounds__(256) void prep_wb(const float* __restrict__ A_diag,
    const float* __restrict__ B, const float* __restrict__ C, const float* __restrict__ D,
    ushort* __restrict__ Wt, ushort* __restrict__ Btu, float* __restrict__ aSig) {
  __shared__ float tile[64][65];
  int bid = blockIdx.x;
  int tid = threadIdx.x;
  int r = tid >> 2;
  if (bid < 272) {
    int bk = bid % 17, bn = bid / 17;
    int k0 = bk * 64, n0 = bn * 64;
    const float* srow = (k0 + r < DSTATE)
        ? (C + (size_t)(k0 + r) * DMODEL + n0)
        : (D + (size_t)(k0 + r - DSTATE) * DMODEL + n0);
#pragma unroll
    for (int it = 0; it < 4; ++it) {
      int c4 = (tid & 3) + it * 4;
      float4 v = *reinterpret_cast<const float4*>(srow + c4 * 4);
      tile[r][c4 * 4 + 0] = v.x; tile[r][c4 * 4 + 1] = v.y;
      tile[r][c4 * 4 + 2] = v.z; tile[r][c4 * 4 + 3] = v.w;
    }
    __syncthreads();
#pragma unroll
    for (int it = 0; it < 2; ++it) {
      int gq = (tid & 3) + it * 4;  // 8-k group 0..7
      ushort o[8];
#pragma unroll
      for (int j = 0; j < 8; ++j) o[j] = f2b(tile[gq * 8 + j][r]);
      *reinterpret_cast<uint4*>(&Wt[(size_t)(n0 + r) * KBIG + k0 + gq * 8]) =
          *reinterpret_cast<uint4*>(o);
    }
  } else {
    int k0 = (bid - 272) * 64;
    const float* srow = B + (size_t)(k0 + r) * DSTATE;
#pragma unroll
    for (int it = 0; it < 4; ++it) {
      int c4 = (tid & 3) + it * 4;
      float4 v = *reinterpret_cast<const float4*>(srow + c4 * 4);
      tile[r][c4 * 4 + 0] = v.x; tile[r][c4 * 4 + 1] = v.y;
      tile[r][c4 * 4 + 2] = v.z; tile[r][c4 * 4 + 3] = v.w;
    }
    __syncthreads();
#pragma unroll
    for (int it = 0; it < 2; ++it) {
      int gq = (tid & 3) + it * 4;
      ushort o[8];
#pragma unroll
      for (int j = 0; j < 8; ++j) o[j] = f2b(tile[gq * 8 + j][r]);
      *reinterpret_cast<uint4*>(&Btu[(size_t)r * DMODEL + k0 + gq * 8]) =
          *reinterpret_cast<uint4*>(o);
    }
    if (bid == 272 && tid < DSTATE) aSig[tid] = 1.0f / (1.0f + expf(-A_diag[tid]));
  }
}

// ---------------- fused (barrier-free): x -> Z(bf16), u = x@B, chunk-local scan --------
// 4 waves/block, each wave OWNS 16 rows + its private As/Ul slices -> zero
// __syncthreads (same-wave DS ops are FIFO-ordered). Waves run skewed.
__global__ __launch_bounds__(256) void fused_xu(const float* __restrict__ x,
    const ushort* __restrict__ Btu, const float* __restrict__ aSig,
    ushort* __restrict__ Z, float* __restrict__ Uloc, float* __restrict__ carry) {
  __shared__ ushort As[4][16][136];
  __shared__ float  Ul[4][16][68];
  int tid = threadIdx.x;
  int w = tid >> 6, lane = tid & 63;
  int l16 = lane & 15, lh = lane >> 4;
  int row0 = blockIdx.x * 64 + w * 16;   // wave-private 16 rows = one scan chunk

  f32x4 acc[4] = {};
  float4 xv[4][2];
#pragma unroll
  for (int p = 0; p < 4; ++p) {
    int fi = p * 64 + lane;
    int r = fi >> 4, g8 = fi & 15;
    const float* src = x + (size_t)(row0 + r) * 1024 + g8 * 8;
    xv[p][0] = *reinterpret_cast<const float4*>(src);
    xv[p][1] = *reinterpret_cast<const float4*>(src + 4);
  }
  for (int c = 0; c < 8; ++c) {
    int k0 = c * 128;
#pragma unroll
    for (int p = 0; p < 4; ++p) {
      int fi = p * 64 + lane;
      int r = fi >> 4, g8 = fi & 15;
      ushort o[8] = {f2b(xv[p][0].x), f2b(xv[p][0].y), f2b(xv[p][0].z), f2b(xv[p][0].w),
                     f2b(xv[p][1].x), f2b(xv[p][1].y), f2b(xv[p][1].z), f2b(xv[p][1].w)};
      uint4 pk = *reinterpret_cast<uint4*>(o);
      *reinterpret_cast<uint4*>(&Z[(size_t)(row0 + r) * KBIG + DSTATE + k0 + g8 * 8]) = pk;
      *reinterpret_cast<uint4*>(&As[w][r][g8 * 8]) = pk;
    }
    if (c < 7) {
      int k1 = k0 + 128;
#pragma unroll
      for (int p = 0; p < 4; ++p) {
        int fi = p * 64 + lane;
        int r = fi >> 4, g8 = fi & 15;
        const float* src = x + (size_t)(row0 + r) * 1024 + k1 + g8 * 8;
        xv[p][0] = *reinterpret_cast<const float4*>(src);
        xv[p][1] = *reinterpret_cast<const float4*>(src + 4);
      }
    }
#pragma unroll
    for (int ks = 0; ks < 4; ++ks) {
      bf16x8 af = *reinterpret_cast<const bf16x8*>(&As[w][l16][ks * 32 + lh * 8]);
#pragma unroll
      for (int n = 0; n < 4; ++n) {
        bf16x8 bf = *reinterpret_cast<const bf16x8*>(
            &Btu[(size_t)(n * 16 + l16) * 1024 + k0 + ks * 32 + lh * 8]);
        acc[n] = __builtin_amdgcn_mfma_f32_16x16x32_bf16(af, bf, acc[n], 0, 0, 0);
      }
    }
  }
#pragma unroll
  for (int n = 0; n < 4; ++n)
#pragma unroll
    for (int j = 0; j < 4; ++j)
      Ul[w][lh * 4 + j][n * 16 + l16] = acc[n][j];
  int s = lane;
  float as = aSig[s];
  float h = 0.0f;
  int g = blockIdx.x * 4 + w;
#pragma unroll
  for (int i = 0; i < 16; ++i) {
    h = fmaf(as, h, Ul[w][i][s]);
    Uloc[(size_t)(g * 16 + i) * 64 + s] = h;
  }
  carry[(size_t)g * 64 + s] = h;
}

// ---------------- scan fix (merged): redundant batched prefix + apply + write Z ------
__global__ __launch_bounds__(256) void scan_fix2(const float* __restrict__ aSig,
    const float* __restrict__ Uloc, const float* __restrict__ carry,
    ushort* __restrict__ Z) {
  int w = threadIdx.x >> 6, s = threadIdx.x & 63;
  int g = blockIdx.x * 4 + w;          // 0..1023
  int b = g >> 8, c = g & 255;
  float as = aSig[s];
  float aL = as;
#pragma unroll
  for (int q = 0; q < 4; ++q) aL *= aL;  // as^16
  const float* cb = carry + ((size_t)b << 8) * 64 + s;
  float H = 0.0f;
  for (int c0 = 0; c0 < 256; c0 += 16) {
    if (c0 >= c) break;                  // wave-uniform
    float v[16];
#pragma unroll
    for (int i = 0; i < 16; ++i) v[i] = cb[(size_t)(c0 + i) * 64];
#pragma unroll
    for (int i = 0; i < 16; ++i)
      if (c0 + i < c) H = fmaf(aL, H, v[i]);   // wave-uniform predicate
  }
  float p = as;
  size_t ubase = (size_t)g * 16 * 64 + s;
  size_t zbase = (size_t)(g * 16) * KBIG + s;
#pragma unroll
  for (int i = 0; i < 16; ++i) {
    float h = fmaf(p, H, Uloc[ubase + (size_t)i * 64]);
    p *= as;
    Z[zbase + (size_t)i * KBIG] = f2b(h);
  }
}

// ---------------- 256x256 8-phase GEMM: y = Z @ Wt^T (R5/R8-proven, best measured) ------
__global__ __launch_bounds__(512) void gemm256(const ushort* __restrict__ A, int lda,
                                               const ushort* __restrict__ Bt, int ldb,
                                               float* __restrict__ Cc, int ldc, int K) {
  extern __shared__ __align__(128) char smem[];
  const int tid = threadIdx.x;
  const int wid = tid >> 6, lane = tid & 63;
  const int wm = wid >> 2, wn = wid & 3;
  const int l16 = lane & 15, lh = lane >> 4;

  int bid = blockIdx.x;
  int swz = (bid & 7) * ((int)gridDim.x >> 3) + (bid >> 3);
  const int bmRow = (swz >> 2) * 256;
  const int bnCol = (swz & 3) * 256;

  const int NT = K / 64;

  const int cswz = ((lh ^ (l16 & 7)) << 4);
  const int sRow = lane >> 3;
  const int sCol = (((lane & 7) ^ (lane >> 3)) << 3);

  f32x4 acc[8][4] = {};
  bf16x8 aR[8], bR[8];

  auto stageA = [&](int buf, int t, int h) {
    size_t r = (size_t)(bmRow + h * 128 + wid * 8 + sRow);
    const ushort* g0 = A + r * (size_t)lda + t * 64 + sCol;
    const char* d = smem + buf * 65536 + (h * 128 + wid * 8) * 128;
    gld_lds16(g0, d);
    gld_lds16(g0 + (size_t)64 * lda, d + 64 * 128);
  };
  auto stageB = [&](int buf, int t, int h) {
    size_t r = (size_t)(bnCol + h * 128 + wid * 8 + sRow);
    const ushort* g0 = Bt + r * (size_t)ldb + t * 64 + sCol;
    const char* d = smem + buf * 65536 + 32768 + (h * 128 + wid * 8) * 128;
    gld_lds16(g0, d);
    gld_lds16(g0 + (size_t)64 * ldb, d + 64 * 128);
  };
  auto loadA = [&](int buf, int qm) {
#pragma unroll
    for (int m = 0; m < 4; ++m)
#pragma unroll
      for (int ks = 0; ks < 2; ++ks)
        aR[m * 2 + ks] = *reinterpret_cast<const bf16x8*>(
            smem + buf * 65536 + (wm * 128 + qm * 64 + m * 16 + l16) * 128 + (cswz ^ (ks * 64)));
  };
  auto loadB = [&](int buf, int qn) {
#pragma unroll
    for (int n = 0; n < 2; ++n)
#pragma unroll
      for (int ks = 0; ks < 2; ++ks)
        bR[qn * 4 + n * 2 + ks] = *reinterpret_cast<const bf16x8*>(
            smem + buf * 65536 + 32768 + (wn * 64 + qn * 32 + n * 16 + l16) * 128 + (cswz ^ (ks * 64)));
  };
  auto mfmaQ = [&](int qm, int qn) {
    __builtin_amdgcn_s_setprio(1);
    __builtin_amdgcn_sched_barrier(0);
#pragma unroll
    for (int ks = 0; ks < 2; ++ks)
#pragma unroll
      for (int m = 0; m < 4; ++m)
#pragma unroll
        for (int n = 0; n < 2; ++n)
          acc[qm * 4 + m][qn * 2 + n] = __builtin_amdgcn_mfma_f32_16x16x32_bf16(
              aR[m * 2 + ks], bR[qn * 4 + n * 2 + ks], acc[qm * 4 + m][qn * 2 + n], 0, 0, 0);
    __builtin_amdgcn_sched_barrier(0);
    __builtin_amdgcn_s_setprio(0);
  };

  stageA(0, 0, 0); stageA(0, 0, 1); stageB(0, 0, 0); stageB(0, 0, 1);
  if (1 < NT) { stageA(1, 1, 0); stageA(1, 1, 1); stageB(1, 1, 0); stageB(1, 1, 1); }
  VMCNT0();
  BARRIER();

  for (int t = 0; t < NT; t += 2) {
    const bool s01 = (t > 0) && (t + 1 < NT);
    const bool s23 = (t + 2 < NT);
    const bool s67 = (t + 3 < NT);
    loadA(0, 0); loadB(0, 0);
    if (s01) stageA(1, t + 1, 0);
    BARRIER(); mfmaQ(0, 0); BARRIER();
    loadB(0, 1);
    if (s01) stageA(1, t + 1, 1);
    BARRIER(); mfmaQ(0, 1); BARRIER();
    loadA(0, 1);
    if (s23) stageB(0, t + 2, 0);
    BARRIER(); mfmaQ(1, 0); BARRIER();
    if (s23) stageB(0, t + 2, 1);
    BARRIER(); mfmaQ(1, 1);
    if (s23) { VMCNT4(); } else { VMCNT0(); }
    BARRIER();
    if (t + 1 < NT) {
      loadA(1, 0); loadB(1, 0);
      if (s23) stageA(0, t + 2, 0);
      BARRIER(); mfmaQ(0, 0); BARRIER();
      loadB(1, 1);
      if (s23) stageA(0, t + 2, 1);
      BARRIER(); mfmaQ(0, 1); BARRIER();
      loadA(1, 1);
      if (s67) stageB(1, t + 3, 0);
      BARRIER(); mfmaQ(1, 0); BARRIER();
      if (s67) stageB(1, t + 3, 1);
      BARRIER(); mfmaQ(1, 1);
      if (s67) { VMCNT4(); } else { VMCNT0(); }
      BARRIER();
    }
  }

#pragma unroll
  for (int i = 0; i < 8; ++i)
#pragma unroll
    for (int jn = 0; jn < 4; ++jn)
#pragma unroll
      for (int j = 0; j < 4; ++j) {
        int r = bmRow + wm * 128 + (i >> 2) * 64 + (i & 3) * 16 + lh * 4 + j;
        int c = bnCol + wn * 64 + (jn >> 1) * 32 + (jn & 1) * 16 + l16;
        Cc[(size_t)r * ldc + c] = acc[i][jn][j];
      }
}

extern "C" void kernel_launch(void* const* d_in, const int* in_sizes, int n_in,
                              void* d_out, int out_size, void* d_ws, size_t ws_size,
                              hipStream_t stream) {
  const float* x      = (const float*)d_in[0];
  const float* A_diag = (const float*)d_in[1];
  const float* B      = (const float*)d_in[2];
  const float* C      = (const float*)d_in[3];
  const float* D      = (const float*)d_in[4];
  float* y = (float*)d_out;

  char* w = (char*)d_ws;
  ushort* Z     = (ushort*)(w);                 // [16384][1088] bf16  35,651,584
  ushort* Wt    = (ushort*)(w + 35651584);      // [1024][1088] bf16    2,228,224
  ushort* Btu   = (ushort*)(w + 37879808);      // [64][1024] bf16        131,072
  float*  Uloc  = (float*) (w + 38010880);      // [16384][64] f32      4,194,304
  float*  carry = (float*) (w + 42205184);      // [1024][64] f32         262,144
  float*  aSig  = (float*) (w + 42467328);      // [64] f32

  (void)hipFuncSetAttribute(reinterpret_cast<const void*>(&gemm256),
                            hipFuncAttributeMaxDynamicSharedMemorySize, 131072);

  prep_wb<<<dim3(288), dim3(256), 0, stream>>>(A_diag, B, C, D, Wt, Btu, aSig);
  fused_xu<<<dim3(256), dim3(256), 0, stream>>>(x, Btu, aSig, Z, Uloc, carry);
  scan_fix2<<<dim3(256), dim3(256), 0, stream>>>(aSig, Uloc, carry, Z);
  // y = [h|x] @ [C;D] : M=16384, N=1024, K=1088  (256x256 tiles -> 256 blocks)
  gemm256<<<dim3(64 * 4), dim3(512), 131072, stream>>>(Z, KBIG, Wt, KBIG, y, DMODEL, KBIG);
}

// Round 13
// 84.845 us; speedup vs baseline: 1.6777x; 1.1350x over previous
//
#include <hip/hip_runtime.h>
#include <hip/hip_bf16.h>

using bf16x8 = __attribute__((ext_vector_type(8))) __bf16;
using f32x4  = __attribute__((ext_vector_type(4))) float;

#define MTOT   16384
#define DMODEL 1024
#define DSTATE 64
#define KBIG   1088

__device__ __forceinline__ ushort f2b(float f) {
  __hip_bfloat16 h = __float2bfloat16(f);
  return *reinterpret_cast<ushort*>(&h);
}

// async global->LDS, 16 bytes per lane. LDS dest = wave-uniform base + lane*16.
__device__ __forceinline__ void gld_lds16(const ushort* g, const char* l) {
  using gptr_t = const __attribute__((address_space(1))) uint32_t*;
  using lptr_t = __attribute__((address_space(3))) uint32_t*;
  __builtin_amdgcn_global_load_lds(
      reinterpret_cast<gptr_t>(reinterpret_cast<uintptr_t>(g)),
      reinterpret_cast<lptr_t>(static_cast<uint32_t>(reinterpret_cast<uintptr_t>(l))),
      16, 0, 0);
}

#define BARRIER() do { asm volatile("" ::: "memory"); __builtin_amdgcn_s_barrier(); asm volatile("" ::: "memory"); } while (0)
#define VMCNT4() asm volatile("s_waitcnt vmcnt(4)" ::: "memory")
#define VMCNT0() asm volatile("s_waitcnt vmcnt(0)" ::: "memory")

// ---------------- prep: coalesced tile-transpose for Wt, Btu; aSig (R12-proven) --------
__global__ __launch_bounds__(256) void prep_wb(const float* __restrict__ A_diag,
    const float* __restrict__ B, const float* __restrict__ C, const float* __restrict__ D,
    ushort* __restrict__ Wt, ushort* __restrict__ Btu, float* __restrict__ aSig) {
  __shared__ float tile[64][65];
  int bid = blockIdx.x;
  int tid = threadIdx.x;
  int r = tid >> 2;
  if (bid < 272) {
    int bk = bid % 17, bn = bid / 17;
    int k0 = bk * 64, n0 = bn * 64;
    const float* srow = (k0 + r < DSTATE)
        ? (C + (size_t)(k0 + r) * DMODEL + n0)
        : (D + (size_t)(k0 + r - DSTATE) * DMODEL + n0);
#pragma unroll
    for (int it = 0; it < 4; ++it) {
      int c4 = (tid & 3) + it * 4;
      float4 v = *reinterpret_cast<const float4*>(srow + c4 * 4);
      tile[r][c4 * 4 + 0] = v.x; tile[r][c4 * 4 + 1] = v.y;
      tile[r][c4 * 4 + 2] = v.z; tile[r][c4 * 4 + 3] = v.w;
    }
    __syncthreads();
#pragma unroll
    for (int it = 0; it < 2; ++it) {
      int gq = (tid & 3) + it * 4;  // 8-k group 0..7
      ushort o[8];
#pragma unroll
      for (int j = 0; j < 8; ++j) o[j] = f2b(tile[gq * 8 + j][r]);
      *reinterpret_cast<uint4*>(&Wt[(size_t)(n0 + r) * KBIG + k0 + gq * 8]) =
          *reinterpret_cast<uint4*>(o);
    }
  } else {
    int k0 = (bid - 272) * 64;
    const float* srow = B + (size_t)(k0 + r) * DSTATE;
#pragma unroll
    for (int it = 0; it < 4; ++it) {
      int c4 = (tid & 3) + it * 4;
      float4 v = *reinterpret_cast<const float4*>(srow + c4 * 4);
      tile[r][c4 * 4 + 0] = v.x; tile[r][c4 * 4 + 1] = v.y;
      tile[r][c4 * 4 + 2] = v.z; tile[r][c4 * 4 + 3] = v.w;
    }
    __syncthreads();
#pragma unroll
    for (int it = 0; it < 2; ++it) {
      int gq = (tid & 3) + it * 4;
      ushort o[8];
#pragma unroll
      for (int j = 0; j < 8; ++j) o[j] = f2b(tile[gq * 8 + j][r]);
      *reinterpret_cast<uint4*>(&Btu[(size_t)r * DMODEL + k0 + gq * 8]) =
          *reinterpret_cast<uint4*>(o);
    }
    if (bid == 272 && tid < DSTATE) aSig[tid] = 1.0f / (1.0f + expf(-A_diag[tid]));
  }
}

// ---------------- fused (R8/R10-proven cooperative): x -> Z(bf16), u = x@B, scan -------
// Block = 64 rows, 4 waves, cooperative loads + 2 barriers/chunk: next-chunk x-loads
// issue BEFORE barrier+MFMA (cross-wave latency hiding at 1 block/CU).
__global__ __launch_bounds__(256) void fused_xu(const float* __restrict__ x,
    const ushort* __restrict__ Btu, const float* __restrict__ aSig,
    ushort* __restrict__ Z, float* __restrict__ Uloc, float* __restrict__ carry) {
  __shared__ ushort As[64][136];
  __shared__ float  Ul[64][68];
  int tid = threadIdx.x;
  int w = tid >> 6, lane = tid & 63;
  int l16 = lane & 15, lh = lane >> 4;
  int row0 = blockIdx.x * 64;

  f32x4 acc[4] = {};
  float4 xv[4][2];
#pragma unroll
  for (int p = 0; p < 4; ++p) {
    int fi = p * 256 + tid;
    int r = fi >> 4, kq = fi & 15;
    const float* src = x + (size_t)(row0 + r) * 1024 + kq * 8;
    xv[p][0] = *reinterpret_cast<const float4*>(src);
    xv[p][1] = *reinterpret_cast<const float4*>(src + 4);
  }
  for (int c = 0; c < 8; ++c) {
    int k0 = c * 128;
#pragma unroll
    for (int p = 0; p < 4; ++p) {
      int fi = p * 256 + tid;
      int r = fi >> 4, kq = fi & 15;
      ushort o[8] = {f2b(xv[p][0].x), f2b(xv[p][0].y), f2b(xv[p][0].z), f2b(xv[p][0].w),
                     f2b(xv[p][1].x), f2b(xv[p][1].y), f2b(xv[p][1].z), f2b(xv[p][1].w)};
      uint4 pk = *reinterpret_cast<uint4*>(o);
      *reinterpret_cast<uint4*>(&Z[(size_t)(row0 + r) * KBIG + DSTATE + k0 + kq * 8]) = pk;
      *reinterpret_cast<uint4*>(&As[r][kq * 8]) = pk;
    }
    __syncthreads();
    if (c < 7) {
      int k1 = k0 + 128;
#pragma unroll
      for (int p = 0; p < 4; ++p) {
        int fi = p * 256 + tid;
        int r = fi >> 4, kq = fi & 15;
        const float* src = x + (size_t)(row0 + r) * 1024 + k1 + kq * 8;
        xv[p][0] = *reinterpret_cast<const float4*>(src);
        xv[p][1] = *reinterpret_cast<const float4*>(src + 4);
      }
    }
#pragma unroll
    for (int ks = 0; ks < 4; ++ks) {
      bf16x8 af = *reinterpret_cast<const bf16x8*>(&As[w * 16 + l16][ks * 32 + lh * 8]);
#pragma unroll
      for (int n = 0; n < 4; ++n) {
        bf16x8 bf = *reinterpret_cast<const bf16x8*>(
            &Btu[(size_t)(n * 16 + l16) * 1024 + k0 + ks * 32 + lh * 8]);
        acc[n] = __builtin_amdgcn_mfma_f32_16x16x32_bf16(af, bf, acc[n], 0, 0, 0);
      }
    }
    __syncthreads();
  }
#pragma unroll
  for (int n = 0; n < 4; ++n)
#pragma unroll
    for (int j = 0; j < 4; ++j)
      Ul[w * 16 + lh * 4 + j][n * 16 + l16] = acc[n][j];
  __syncthreads();
  int s = lane;
  float as = aSig[s];
  float h = 0.0f;
  int g = blockIdx.x * 4 + w;
#pragma unroll
  for (int i = 0; i < 16; ++i) {
    h = fmaf(as, h, Ul[w * 16 + i][s]);
    Uloc[(size_t)(g * 16 + i) * 64 + s] = h;
  }
  carry[(size_t)g * 64 + s] = h;
}

// ---------------- scan fix (merged): redundant batched prefix + apply + write Z ------
__global__ __launch_bounds__(256) void scan_fix2(const float* __restrict__ aSig,
    const float* __restrict__ Uloc, const float* __restrict__ carry,
    ushort* __restrict__ Z) {
  int w = threadIdx.x >> 6, s = threadIdx.x & 63;
  int g = blockIdx.x * 4 + w;          // 0..1023
  int b = g >> 8, c = g & 255;
  float as = aSig[s];
  float aL = as;
#pragma unroll
  for (int q = 0; q < 4; ++q) aL *= aL;  // as^16
  const float* cb = carry + ((size_t)b << 8) * 64 + s;
  float H = 0.0f;
  for (int c0 = 0; c0 < 256; c0 += 16) {
    if (c0 >= c) break;                  // wave-uniform
    float v[16];
#pragma unroll
    for (int i = 0; i < 16; ++i) v[i] = cb[(size_t)(c0 + i) * 64];
#pragma unroll
    for (int i = 0; i < 16; ++i)
      if (c0 + i < c) H = fmaf(aL, H, v[i]);   // wave-uniform predicate
  }
  float p = as;
  size_t ubase = (size_t)g * 16 * 64 + s;
  size_t zbase = (size_t)(g * 16) * KBIG + s;
#pragma unroll
  for (int i = 0; i < 16; ++i) {
    float h = fmaf(p, H, Uloc[ubase + (size_t)i * 64]);
    p *= as;
    Z[zbase + (size_t)i * KBIG] = f2b(h);
  }
}

// ---------------- 256x256 8-phase GEMM: y = Z @ Wt^T (R5/R8-proven, best measured) ------
__global__ __launch_bounds__(512) void gemm256(const ushort* __restrict__ A, int lda,
                                               const ushort* __restrict__ Bt, int ldb,
                                               float* __restrict__ Cc, int ldc, int K) {
  extern __shared__ __align__(128) char smem[];
  const int tid = threadIdx.x;
  const int wid = tid >> 6, lane = tid & 63;
  const int wm = wid >> 2, wn = wid & 3;
  const int l16 = lane & 15, lh = lane >> 4;

  int bid = blockIdx.x;
  int swz = (bid & 7) * ((int)gridDim.x >> 3) + (bid >> 3);
  const int bmRow = (swz >> 2) * 256;
  const int bnCol = (swz & 3) * 256;

  const int NT = K / 64;

  const int cswz = ((lh ^ (l16 & 7)) << 4);
  const int sRow = lane >> 3;
  const int sCol = (((lane & 7) ^ (lane >> 3)) << 3);

  f32x4 acc[8][4] = {};
  bf16x8 aR[8], bR[8];

  auto stageA = [&](int buf, int t, int h) {
    size_t r = (size_t)(bmRow + h * 128 + wid * 8 + sRow);
    const ushort* g0 = A + r * (size_t)lda + t * 64 + sCol;
    const char* d = smem + buf * 65536 + (h * 128 + wid * 8) * 128;
    gld_lds16(g0, d);
    gld_lds16(g0 + (size_t)64 * lda, d + 64 * 128);
  };
  auto stageB = [&](int buf, int t, int h) {
    size_t r = (size_t)(bnCol + h * 128 + wid * 8 + sRow);
    const ushort* g0 = Bt + r * (size_t)ldb + t * 64 + sCol;
    const char* d = smem + buf * 65536 + 32768 + (h * 128 + wid * 8) * 128;
    gld_lds16(g0, d);
    gld_lds16(g0 + (size_t)64 * ldb, d + 64 * 128);
  };
  auto loadA = [&](int buf, int qm) {
#pragma unroll
    for (int m = 0; m < 4; ++m)
#pragma unroll
      for (int ks = 0; ks < 2; ++ks)
        aR[m * 2 + ks] = *reinterpret_cast<const bf16x8*>(
            smem + buf * 65536 + (wm * 128 + qm * 64 + m * 16 + l16) * 128 + (cswz ^ (ks * 64)));
  };
  auto loadB = [&](int buf, int qn) {
#pragma unroll
    for (int n = 0; n < 2; ++n)
#pragma unroll
      for (int ks = 0; ks < 2; ++ks)
        bR[qn * 4 + n * 2 + ks] = *reinterpret_cast<const bf16x8*>(
            smem + buf * 65536 + 32768 + (wn * 64 + qn * 32 + n * 16 + l16) * 128 + (cswz ^ (ks * 64)));
  };
  auto mfmaQ = [&](int qm, int qn) {
    __builtin_amdgcn_s_setprio(1);
    __builtin_amdgcn_sched_barrier(0);
#pragma unroll
    for (int ks = 0; ks < 2; ++ks)
#pragma unroll
      for (int m = 0; m < 4; ++m)
#pragma unroll
        for (int n = 0; n < 2; ++n)
          acc[qm * 4 + m][qn * 2 + n] = __builtin_amdgcn_mfma_f32_16x16x32_bf16(
              aR[m * 2 + ks], bR[qn * 4 + n * 2 + ks], acc[qm * 4 + m][qn * 2 + n], 0, 0, 0);
    __builtin_amdgcn_sched_barrier(0);
    __builtin_amdgcn_s_setprio(0);
  };

  stageA(0, 0, 0); stageA(0, 0, 1); stageB(0, 0, 0); stageB(0, 0, 1);
  if (1 < NT) { stageA(1, 1, 0); stageA(1, 1, 1); stageB(1, 1, 0); stageB(1, 1, 1); }
  VMCNT0();
  BARRIER();

  for (int t = 0; t < NT; t += 2) {
    const bool s01 = (t > 0) && (t + 1 < NT);
    const bool s23 = (t + 2 < NT);
    const bool s67 = (t + 3 < NT);
    loadA(0, 0); loadB(0, 0);
    if (s01) stageA(1, t + 1, 0);
    BARRIER(); mfmaQ(0, 0); BARRIER();
    loadB(0, 1);
    if (s01) stageA(1, t + 1, 1);
    BARRIER(); mfmaQ(0, 1); BARRIER();
    loadA(0, 1);
    if (s23) stageB(0, t + 2, 0);
    BARRIER(); mfmaQ(1, 0); BARRIER();
    if (s23) stageB(0, t + 2, 1);
    BARRIER(); mfmaQ(1, 1);
    if (s23) { VMCNT4(); } else { VMCNT0(); }
    BARRIER();
    if (t + 1 < NT) {
      loadA(1, 0); loadB(1, 0);
      if (s23) stageA(0, t + 2, 0);
      BARRIER(); mfmaQ(0, 0); BARRIER();
      loadB(1, 1);
      if (s23) stageA(0, t + 2, 1);
      BARRIER(); mfmaQ(0, 1); BARRIER();
      loadA(1, 1);
      if (s67) stageB(1, t + 3, 0);
      BARRIER(); mfmaQ(1, 0); BARRIER();
      if (s67) stageB(1, t + 3, 1);
      BARRIER(); mfmaQ(1, 1);
      if (s67) { VMCNT4(); } else { VMCNT0(); }
      BARRIER();
    }
  }

#pragma unroll
  for (int i = 0; i < 8; ++i)
#pragma unroll
    for (int jn = 0; jn < 4; ++jn)
#pragma unroll
      for (int j = 0; j < 4; ++j) {
        int r = bmRow + wm * 128 + (i >> 2) * 64 + (i & 3) * 16 + lh * 4 + j;
        int c = bnCol + wn * 64 + (jn >> 1) * 32 + (jn & 1) * 16 + l16;
        Cc[(size_t)r * ldc + c] = acc[i][jn][j];
      }
}

extern "C" void kernel_launch(void* const* d_in, const int* in_sizes, int n_in,
                              void* d_out, int out_size, void* d_ws, size_t ws_size,
                              hipStream_t stream) {
  const float* x      = (const float*)d_in[0];
  const float* A_diag = (const float*)d_in[1];
  const float* B      = (const float*)d_in[2];
  const float* C      = (const float*)d_in[3];
  const float* D      = (const float*)d_in[4];
  float* y = (float*)d_out;

  char* w = (char*)d_ws;
  ushort* Z     = (ushort*)(w);                 // [16384][1088] bf16  35,651,584
  ushort* Wt    = (ushort*)(w + 35651584);      // [1024][1088] bf16    2,228,224
  ushort* Btu   = (ushort*)(w + 37879808);      // [64][1024] bf16        131,072
  float*  Uloc  = (float*) (w + 38010880);      // [16384][64] f32      4,194,304
  float*  carry = (float*) (w + 42205184);      // [1024][64] f32         262,144
  float*  aSig  = (float*) (w + 42467328);      // [64] f32

  (void)hipFuncSetAttribute(reinterpret_cast<const void*>(&gemm256),
                            hipFuncAttributeMaxDynamicSharedMemorySize, 131072);

  prep_wb<<<dim3(288), dim3(256), 0, stream>>>(A_diag, B, C, D, Wt, Btu, aSig);
  fused_xu<<<dim3(256), dim3(256), 0, stream>>>(x, Btu, aSig, Z, Uloc, carry);
  scan_fix2<<<dim3(256), dim3(256), 0, stream>>>(aSig, Uloc, carry, Z);
  // y = [h|x] @ [C;D] : M=16384, N=1024, K=1088  (256x256 tiles -> 256 blocks)
  gemm256<<<dim3(64 * 4), dim3(512), 131072, stream>>>(Z, KBIG, Wt, KBIG, y, DMODEL, KBIG);
}